// Round 6
// baseline (190.368 us; speedup 1.0000x reference)
//
#include <hip/hip_runtime.h>
#include <stdint.h>

// Problem constants (fixed by setup_inputs)
#define NROWS 8192
#define DDIM 256
#define NSTRIPS 16
#define STRIP_COLS 512     // NROWS / NSTRIPS
#define BN 32              // cols per LDS tile
#define NTILES 16          // STRIP_COLS / BN
#define BM 128             // rows per block (4 waves x 32 rows)
#define NBLOCKS (NSTRIPS * (NROWS / BM))   // 1024

// Scores are computed directly in log2-units: e is scaled by sqrt(log2(e)/0.7)
// so acc = s*log2(e) and exp(s) == exp2(acc). Since s <= 1/0.7, exp2(acc) <= 4.17
// and per-row sums <= ~34k: no overflow, so NO log-sum-exp shift is needed at all.
#define ESCALE 1.4356159f        // sqrt(log2(e)/0.7)
#define LN2F   0.6931471806f
#define NEGBIG (-1e30f)

// Workspace layout (bytes): [0,256) counter; [256, 256+32K) pm keys (uint);
// [256+32K, 256+64K) neg sums (float); ebf at 65792.
#define WS_PMK   256
#define WS_NS    (256 + 32768)
#define WS_EBF   (256 + 65536)
#define WS_ZERO_BYTES (256 + 65536)

typedef __attribute__((ext_vector_type(8))) short short8;   // 8 bf16 = 4 VGPRs
typedef __attribute__((ext_vector_type(4))) float f32x4;    // MFMA 16x16 accumulator

typedef __attribute__((address_space(3))) void lds_void;          // LDS ptr for DMA builtin
typedef const __attribute__((address_space(1))) void gl_void;     // global ptr for DMA builtin

__device__ __forceinline__ unsigned short f2bf(float x) {   // RNE float->bf16
  unsigned int u = __float_as_uint(x);
  u += 0x7fffu + ((u >> 16) & 1u);
  return (unsigned short)(u >> 16);
}

// Monotone float <-> uint key: a<b (non-NaN) <=> fkey(a)<fkey(b). Zero-init key
// (0x00000000) decodes to -NaN, below every real key -> "never written".
__device__ __forceinline__ unsigned fkey(float f) {
  unsigned b = __float_as_uint(f);
  return (b & 0x80000000u) ? ~b : (b | 0x80000000u);
}
__device__ __forceinline__ float funkey(unsigned k) {
  unsigned b = (k & 0x80000000u) ? (k & 0x7fffffffu) : ~k;
  return __uint_as_float(b);
}

// ---------------- Kernel 1: row L2-normalize -> scaled bf16 (+init) ----------------
// Block 0 additionally zeroes the counter + pm/ns partial region (replaces the
// hipMemsetAsync dispatch; visible to kmain via the inter-dispatch dependency).
__global__ __launch_bounds__(256) void knorm(const float* __restrict__ emb,
                                             unsigned short* __restrict__ ebf,
                                             uint4* __restrict__ zbase) {
  if (blockIdx.x == 0) {
    const uint4 z = {0u, 0u, 0u, 0u};
    for (int i = threadIdx.x; i < WS_ZERO_BYTES / 16; i += 256) zbase[i] = z;
  }
  const int wave = threadIdx.x >> 6, lane = threadIdx.x & 63;
  const int row = blockIdx.x * 4 + wave;              // one wave per row
  const float4 v = *(const float4*)(emb + row * DDIM + lane * 4);
  float ss = v.x * v.x + v.y * v.y + v.z * v.z + v.w * v.w;
#pragma unroll
  for (int off = 1; off < 64; off <<= 1) ss += __shfl_xor(ss, off, 64);
  const float sc = rsqrtf(ss) * ESCALE;
  ushort4 o;
  o.x = f2bf(v.x * sc); o.y = f2bf(v.y * sc);
  o.z = f2bf(v.z * sc); o.w = f2bf(v.w * sc);
  *(ushort4*)(ebf + row * DDIM + lane * 4) = o;
}

// ---------------- Kernel 2: fused sims + masked max / sum-of-exp + merge ----------------
// grid = (NSTRIPS, NROWS/BM) = 1024 blocks. LDS = 2 x 16 KB -> 5 blocks/CU.
// NO min-waves launch bound (R4: __launch_bounds__(256,5) forced VGPR=48 and spilled
// a[2][8] -> 452 MB scratch writes). Unconstrained = 80 VGPR.
// Epilogue: per-row partials merged via device-scope atomics (uint-key max + float
// add); the LAST block (atomic counter) reads the 64 KB merged arrays and computes
// the final loss -- the kmerge kernel and its launch gap are gone.
__global__ __launch_bounds__(256) void kmain(const unsigned short* __restrict__ ebf,
                                             const int* __restrict__ cats,
                                             unsigned* __restrict__ pmk,
                                             float* __restrict__ nsum,
                                             int* __restrict__ cnt,
                                             float* __restrict__ out) {
  // B tile: BN cols x 256 k as 16B chunks, chunk p = kc*32 + col at byte p*16.
  __shared__ alignas(16) unsigned short smem[2][BN * DDIM];  // 2 x 16 KB
  __shared__ int isLast;
  __shared__ float red[8];
  const int tid = threadIdx.x;
  const int lane = tid & 63, wave = tid >> 6;
  const int lane15 = lane & 15, quad = lane >> 4;
  const int strip = blockIdx.x, rowTile = blockIdx.y;
  const int rowG = rowTile * BM + wave * 32;          // this wave's 32 rows (m=2)
  const int col0 = strip * STRIP_COLS;

  // A fragments for the whole kernel live in registers: a[m][kk] covers
  // rows rowG+m*16+(lane&15), k = kk*32 + quad*8 .. +7   (64 VGPRs)
  short8 a[2][8];
#pragma unroll
  for (int m = 0; m < 2; ++m)
#pragma unroll
    for (int kk = 0; kk < 8; ++kk)
      a[m][kk] = *(const short8*)(ebf + (rowG + m * 16 + lane15) * DDIM + kk * 32 + quad * 8);

  // Per-lane C-layout row categories: row = quad*4 + r (+ m*16)
  int cati[2][4];
#pragma unroll
  for (int m = 0; m < 2; ++m)
#pragma unroll
    for (int r = 0; r < 4; ++r)
      cati[m][r] = cats[rowG + m * 16 + quad * 4 + r];

  // Is this lane the diagonal element (row==col) within a diagonal 16x16 tile?
  bool dlr[4];
#pragma unroll
  for (int r = 0; r < 4; ++r) dlr[r] = (lane15 == quad * 4 + r);

  float pm[2][4], ns[2][4];
#pragma unroll
  for (int m = 0; m < 2; ++m)
#pragma unroll
    for (int r = 0; r < 4; ++r) { pm[m][r] = NEGBIG; ns[m][r] = 0.f; }

  // Async-stage one B tile (1024 16B chunks) into buffer `buf`: 4 DMA per thread.
  // Thread (w,l) takes chunks p = c*256 + w*64 + l; LDS byte = p*16 decomposes as
  // wave-uniform (c*4096 + w*1024) + l*16. Global: kc = c*8 + w*2 + (l>>5), col = l&31.
#define STAGE(t, buf)                                                           \
  {                                                                             \
    const unsigned short* g = ebf +                                             \
        (size_t)(col0 + (t) * BN + (lane & 31)) * DDIM +                        \
        (wave * 2 + (lane >> 5)) * 8;                                           \
    char* lb = (char*)&smem[(buf)][0] + wave * 1024;                            \
    _Pragma("unroll")                                                           \
    for (int c = 0; c < 4; ++c)                                                 \
      __builtin_amdgcn_global_load_lds((gl_void*)(g + c * 64),                  \
                                       (lds_void*)(lb + c * 4096), 16, 0, 0);   \
  }

  STAGE(0, 0);

  for (int t = 0; t < NTILES; ++t) {
    __syncthreads();                       // tile t's DMA drained; prev reads done
    if (t + 1 < NTILES) STAGE(t + 1, (t + 1) & 1);   // overlaps this tile's MFMA
    const char* bb = (const char*)&smem[t & 1][0];
    const int colBase = col0 + t * BN;
    const int cjt[2] = {cats[colBase + lane15], cats[colBase + 16 + lane15]};

#pragma unroll
    for (int nt = 0; nt < 2; ++nt) {
      // Batch the 8 B-fragment reads ahead of the MFMA cluster: one latency +
      // pipelined ds_reads instead of a serial read->use chain.
      short8 b[8];
#pragma unroll
      for (int kk = 0; kk < 8; ++kk)
        b[kk] = *(const short8*)(bb + kk * 2048 + quad * 512 + nt * 256 + lane15 * 16);
      f32x4 acc0 = {0.f, 0.f, 0.f, 0.f}, acc1 = {0.f, 0.f, 0.f, 0.f};
      __builtin_amdgcn_s_setprio(1);       // T5: favor MFMA-issuing wave
#pragma unroll
      for (int kk = 0; kk < 8; ++kk) {
        acc0 = __builtin_amdgcn_mfma_f32_16x16x32_bf16(a[0][kk], b[kk], acc0, 0, 0, 0);
        acc1 = __builtin_amdgcn_mfma_f32_16x16x32_bf16(a[1][kk], b[kk], acc1, 0, 0, 0);
      }
      __builtin_amdgcn_s_setprio(0);
      const int cj = cjt[nt];
      // Wave-uniform: does this 16x16 tile sit on the global diagonal?
      const bool dg0 = (rowG == colBase + nt * 16);
      const bool dg1 = (rowG + 16 == colBase + nt * 16);
#pragma unroll
      for (int m = 0; m < 2; ++m) {
        const bool dg = m ? dg1 : dg0;
#pragma unroll
        for (int r = 0; r < 4; ++r) {
          const float s = m ? acc1[r] : acc0[r];      // score in log2-units
          const float e = __builtin_amdgcn_exp2f(s);
          const bool same = (cj == cati[m][r]);
          float psv = same ? s : NEGBIG;              // positive candidate
          if (dg) psv = dlr[r] ? NEGBIG : psv;        // exclude self (rare branch)
          pm[m][r] = fmaxf(pm[m][r], psv);
          ns[m][r] += same ? 0.f : e;                 // negative sum-of-exp
        }
      }
    }
  }

  // Reduce across the 16 lanes of each quad (they share rows quad*4+r).
#pragma unroll
  for (int off = 1; off < 16; off <<= 1) {
#pragma unroll
    for (int m = 0; m < 2; ++m)
#pragma unroll
      for (int r = 0; r < 4; ++r) {
        pm[m][r] = fmaxf(pm[m][r], __shfl_xor(pm[m][r], off, 64));
        ns[m][r] += __shfl_xor(ns[m][r], off, 64);
      }
  }
  // Merge this block's partials into the global per-row accumulators.
  if (lane15 == 0) {
#pragma unroll
    for (int m = 0; m < 2; ++m)
#pragma unroll
      for (int r = 0; r < 4; ++r) {
        const int row = rowG + m * 16 + quad * 4 + r;
        atomicMax(&pmk[row], fkey(pm[m][r]));
        atomicAdd(&nsum[row], ns[m][r]);
      }
    __threadfence();                       // my merges visible before counter bump
  }
  __syncthreads();
  if (tid == 0) {
    const int prev = atomicAdd(cnt, 1);
    isLast = (prev == NBLOCKS - 1);
  }
  __syncthreads();
  if (isLast) {                            // last block computes the final loss
    float lsum = 0.f, csum = 0.f;
    for (int i = tid; i < NROWS; i += 256) {
      const unsigned k = atomicOr(&pmk[i], 0u);      // coherent reads
      const float nsv = atomicAdd(&nsum[i], 0.f);
      const float pmv = funkey(k);
      const bool valid = (pmv > -1e29f) && (nsv > 0.f);
      lsum += valid ? (logf(__builtin_amdgcn_exp2f(pmv) + nsv) - pmv * LN2F) : 0.f;
      csum += valid ? 1.f : 0.f;
    }
#pragma unroll
    for (int off = 1; off < 64; off <<= 1) {
      lsum += __shfl_xor(lsum, off, 64);
      csum += __shfl_xor(csum, off, 64);
    }
    if (lane == 0) { red[wave * 2] = lsum; red[wave * 2 + 1] = csum; }
    __syncthreads();
    if (tid == 0) {
      const float L = red[0] + red[2] + red[4] + red[6];
      const float C = red[1] + red[3] + red[5] + red[7];
      out[0] = L / fmaxf(C, 1.f);
    }
  }
}

// ---------------- Launch ----------------
extern "C" void kernel_launch(void* const* d_in, const int* in_sizes, int n_in,
                              void* d_out, int out_size, void* d_ws, size_t ws_size,
                              hipStream_t stream) {
  const float* emb = (const float*)d_in[0];
  const int* cats = (const int*)d_in[1];
  // d_in[2] (font_labels) is unused by the reference.
  float* out = (float*)d_out;

  char* ws = (char*)d_ws;
  int* cnt = (int*)ws;                                       // block counter (ws+0)
  unsigned* pmk = (unsigned*)(ws + WS_PMK);                  // per-row max keys
  float* nsum = (float*)(ws + WS_NS);                        // per-row neg sums
  unsigned short* ebf = (unsigned short*)(ws + WS_EBF);      // 4 MB bf16 normalized

  knorm<<<NROWS / 4, 256, 0, stream>>>(emb, ebf, (uint4*)ws);
  kmain<<<dim3(NSTRIPS, NROWS / BM), 256, 0, stream>>>(ebf, cats, pmk, nsum, cnt, out);
}

// Round 7
// 141.230 us; speedup vs baseline: 1.3479x; 1.3479x over previous
//
#include <hip/hip_runtime.h>
#include <stdint.h>

// Problem constants (fixed by setup_inputs)
#define NROWS 8192
#define DDIM 256
#define RB 128             // rows/cols per symmetric block
#define NRB (NROWS / RB)   // 64 block-rows -> 64x64 triangular grid
#define BN 32              // cols per LDS tile
#define NTILES (RB / BN)   // 4 tiles per block
#define NSLOT NRB          // 64 partial slots per row

// Scores are computed directly in log2-units: e is scaled by sqrt(log2(e)/0.7)
// so acc = s*log2(e) and exp(s) == exp2(acc). Since s <= 1/0.7, exp2(acc) <= 4.17
// and per-row sums <= ~34k: no overflow, so NO log-sum-exp shift is needed at all.
#define ESCALE 1.4356159f        // sqrt(log2(e)/0.7)
#define LN2F   0.6931471806f
#define NEGBIG (-1e30f)

typedef __attribute__((ext_vector_type(8))) short short8;   // 8 bf16 = 4 VGPRs
typedef __attribute__((ext_vector_type(4))) float f32x4;    // MFMA 16x16 accumulator

typedef __attribute__((address_space(3))) void lds_void;          // LDS ptr for DMA builtin
typedef const __attribute__((address_space(1))) void gl_void;     // global ptr for DMA builtin

__device__ __forceinline__ unsigned short f2bf(float x) {   // RNE float->bf16
  unsigned int u = __float_as_uint(x);
  u += 0x7fffu + ((u >> 16) & 1u);
  return (unsigned short)(u >> 16);
}

// ---------------- Kernel 1: row L2-normalize -> scaled bf16 ----------------
__global__ __launch_bounds__(256) void knorm(const float* __restrict__ emb,
                                             unsigned short* __restrict__ ebf) {
  const int wave = threadIdx.x >> 6, lane = threadIdx.x & 63;
  const int row = blockIdx.x * 4 + wave;              // one wave per row
  const float4 v = *(const float4*)(emb + row * DDIM + lane * 4);
  float ss = v.x * v.x + v.y * v.y + v.z * v.z + v.w * v.w;
#pragma unroll
  for (int off = 1; off < 64; off <<= 1) ss += __shfl_xor(ss, off, 64);
  const float sc = rsqrtf(ss) * ESCALE;
  ushort4 o;
  o.x = f2bf(v.x * sc); o.y = f2bf(v.y * sc);
  o.z = f2bf(v.z * sc); o.w = f2bf(v.w * sc);
  *(ushort4*)(ebf + row * DDIM + lane * 4) = o;
}

// ---------------- Kernel 2: symmetric fused sims + masked max / sum-of-exp ----------------
// Triangular grid: blockIdx=(J,I), blocks with J<I exit. Off-diagonal blocks use
// s_ij == s_ji to contribute BOTH to rows of I (row path, as before) and rows of J
// (column path: lane-local reduce over m,r -> shfl across quads -> LDS cross-wave).
// Partial slots: rows of I get slot J; rows of J get slot I; diagonal block -> slot I.
// Each (row, slot) is written exactly once -> plain stores, no atomics, no fences
// (R6 lesson: per-block device-scope fences flush the XCD L2 and cost 2.5x).
// NO min-waves launch bound (R4: forcing 5 waves/EU spilled a[2][8] to scratch).
__global__ __launch_bounds__(256) void kmain(const unsigned short* __restrict__ ebf,
                                             const int* __restrict__ cats,
                                             float* __restrict__ posP,
                                             float* __restrict__ sumP) {
  const int I = blockIdx.y, J = blockIdx.x;
  if (J < I) return;                                  // lower triangle: nothing to do
  // B tile: BN cols x 256 k as 16B chunks, chunk p = kc*32 + col at byte p*16.
  __shared__ alignas(16) unsigned short smem[2][BN * DDIM];  // 2 x 16 KB
  __shared__ float cpm[4][RB], cns[4][RB];                   // col partials, 4 KB
  const int tid = threadIdx.x;
  const int lane = tid & 63, wave = tid >> 6;
  const int lane15 = lane & 15, quad = lane >> 4;
  const bool offd = (I != J);
  const int rowG = I * RB + wave * 32;                // this wave's 32 rows (m=2)
  const int col0 = J * RB;

  // A fragments for the whole block live in registers: a[m][kk] covers
  // rows rowG+m*16+(lane&15), k = kk*32 + quad*8 .. +7   (64 VGPRs)
  short8 a[2][8];
#pragma unroll
  for (int m = 0; m < 2; ++m)
#pragma unroll
    for (int kk = 0; kk < 8; ++kk)
      a[m][kk] = *(const short8*)(ebf + (rowG + m * 16 + lane15) * DDIM + kk * 32 + quad * 8);

  // Per-lane C-layout row categories: row = quad*4 + r (+ m*16)
  int cati[2][4];
#pragma unroll
  for (int m = 0; m < 2; ++m)
#pragma unroll
    for (int r = 0; r < 4; ++r)
      cati[m][r] = cats[rowG + m * 16 + quad * 4 + r];

  // Is this lane the diagonal element (row==col) within a diagonal 16x16 tile?
  bool dlr[4];
#pragma unroll
  for (int r = 0; r < 4; ++r) dlr[r] = (lane15 == quad * 4 + r);

  float pm[2][4], ns[2][4];
#pragma unroll
  for (int m = 0; m < 2; ++m)
#pragma unroll
    for (int r = 0; r < 4; ++r) { pm[m][r] = NEGBIG; ns[m][r] = 0.f; }

  // Async-stage one B tile (1024 16B chunks) into buffer `buf`: 4 DMA per thread.
  // Thread (w,l) takes chunks p = c*256 + w*64 + l; LDS byte = p*16 decomposes as
  // wave-uniform (c*4096 + w*1024) + l*16. Global: kc = c*8 + w*2 + (l>>5), col = l&31.
#define STAGE(t, buf)                                                           \
  {                                                                             \
    const unsigned short* g = ebf +                                             \
        (size_t)(col0 + (t) * BN + (lane & 31)) * DDIM +                        \
        (wave * 2 + (lane >> 5)) * 8;                                           \
    char* lb = (char*)&smem[(buf)][0] + wave * 1024;                            \
    _Pragma("unroll")                                                           \
    for (int c = 0; c < 4; ++c)                                                 \
      __builtin_amdgcn_global_load_lds((gl_void*)(g + c * 64),                  \
                                       (lds_void*)(lb + c * 4096), 16, 0, 0);   \
  }

  STAGE(0, 0);

  for (int t = 0; t < NTILES; ++t) {
    __syncthreads();                       // tile t's DMA drained; prev reads done
    if (t + 1 < NTILES) STAGE(t + 1, (t + 1) & 1);   // overlaps this tile's MFMA
    const char* bb = (const char*)&smem[t & 1][0];
    const int colBase = col0 + t * BN;
    const int cjt[2] = {cats[colBase + lane15], cats[colBase + 16 + lane15]};

#pragma unroll
    for (int nt = 0; nt < 2; ++nt) {
      // Batch the 8 B-fragment reads ahead of the MFMA cluster.
      short8 b[8];
#pragma unroll
      for (int kk = 0; kk < 8; ++kk)
        b[kk] = *(const short8*)(bb + kk * 2048 + quad * 512 + nt * 256 + lane15 * 16);
      f32x4 acc0 = {0.f, 0.f, 0.f, 0.f}, acc1 = {0.f, 0.f, 0.f, 0.f};
      __builtin_amdgcn_s_setprio(1);       // T5: favor MFMA-issuing wave
#pragma unroll
      for (int kk = 0; kk < 8; ++kk) {
        acc0 = __builtin_amdgcn_mfma_f32_16x16x32_bf16(a[0][kk], b[kk], acc0, 0, 0, 0);
        acc1 = __builtin_amdgcn_mfma_f32_16x16x32_bf16(a[1][kk], b[kk], acc1, 0, 0, 0);
      }
      __builtin_amdgcn_s_setprio(0);
      const int cj = cjt[nt];
      // Diagonal 16x16 tiles only exist when I==J (row/col ranges overlap).
      const bool dg0 = (rowG == colBase + nt * 16);
      const bool dg1 = (rowG + 16 == colBase + nt * 16);
      float cpmv = NEGBIG, cnsv = 0.f;     // this lane's column partial (col=colBase+nt*16+lane15)
#pragma unroll
      for (int m = 0; m < 2; ++m) {
        const bool dg = m ? dg1 : dg0;
#pragma unroll
        for (int r = 0; r < 4; ++r) {
          const float s = m ? acc1[r] : acc0[r];      // score in log2-units
          const float e = __builtin_amdgcn_exp2f(s);
          const bool same = (cj == cati[m][r]);
          float psv = same ? s : NEGBIG;              // positive candidate
          if (dg) psv = dlr[r] ? NEGBIG : psv;        // exclude self (diag blocks only)
          pm[m][r] = fmaxf(pm[m][r], psv);
          const float ev = same ? 0.f : e;
          ns[m][r] += ev;                             // row negative sum-of-exp
          cpmv = fmaxf(cpmv, psv);                    // col path (symmetry)
          cnsv += ev;
        }
      }
      if (offd) {
        // Reduce col partials across the 4 quads (lanes sharing lane15 hold the
        // same column, different row-subsets), then park in LDS per wave.
        cpmv = fmaxf(cpmv, __shfl_xor(cpmv, 16, 64)); cnsv += __shfl_xor(cnsv, 16, 64);
        cpmv = fmaxf(cpmv, __shfl_xor(cpmv, 32, 64)); cnsv += __shfl_xor(cnsv, 32, 64);
        if (quad == 0) {
          const int c = t * BN + nt * 16 + lane15;
          cpm[wave][c] = cpmv; cns[wave][c] = cnsv;
        }
      }
    }
  }

  // Row path: reduce across the 16 lanes of each quad (they share rows quad*4+r),
  // then store into slot J (plain coalesced-ish stores; each (row,slot) unique).
#pragma unroll
  for (int off = 1; off < 16; off <<= 1) {
#pragma unroll
    for (int m = 0; m < 2; ++m)
#pragma unroll
      for (int r = 0; r < 4; ++r) {
        pm[m][r] = fmaxf(pm[m][r], __shfl_xor(pm[m][r], off, 64));
        ns[m][r] += __shfl_xor(ns[m][r], off, 64);
      }
  }
  if (lane15 == 0) {
#pragma unroll
    for (int m = 0; m < 2; ++m)
#pragma unroll
      for (int r = 0; r < 4; ++r) {
        const int row = rowG + m * 16 + quad * 4 + r;
        posP[J * NROWS + row] = pm[m][r];
        sumP[J * NROWS + row] = ns[m][r];
      }
  }
  // Col path: cross-wave reduce the 128 column partials, store into slot I.
  if (offd) {
    __syncthreads();                       // col LDS writes from all waves done
    if (tid < RB) {
      const float p = fmaxf(fmaxf(cpm[0][tid], cpm[1][tid]),
                            fmaxf(cpm[2][tid], cpm[3][tid]));
      const float n = cns[0][tid] + cns[1][tid] + cns[2][tid] + cns[3][tid];
      posP[I * NROWS + col0 + tid] = p;
      sumP[I * NROWS + col0 + tid] = n;
    }
  }
}

// ---------------- Kernel 3: merge slots, per-row loss, reduce, finalize ----------------
__global__ __launch_bounds__(256) void kmerge(const float* __restrict__ posP,
                                              const float* __restrict__ sumP,
                                              float* __restrict__ acc,
                                              float* __restrict__ out) {
  const int row = blockIdx.x * 256 + threadIdx.x;
  float pm = NEGBIG, ns = 0.f;
#pragma unroll 8
  for (int s = 0; s < NSLOT; ++s) {
    pm = fmaxf(pm, posP[s * NROWS + row]);
    ns += sumP[s * NROWS + row];
  }
  const bool valid = (pm > -1e29f) && (ns > 0.f);
  // pm is pos*log2(e); loss = -pos + ln(exp2(pm) + sum_neg exp(s))   (no shift needed)
  float loss = valid ? (logf(__builtin_amdgcn_exp2f(pm) + ns) - pm * LN2F) : 0.f;
  float cnt = valid ? 1.f : 0.f;
#pragma unroll
  for (int off = 1; off < 64; off <<= 1) {
    loss += __shfl_xor(loss, off, 64);
    cnt += __shfl_xor(cnt, off, 64);
  }
  if ((threadIdx.x & 63) == 0) {
    atomicAdd(&acc[0], loss);
    atomicAdd(&acc[1], cnt);
    __threadfence();                       // my adds visible before the counter bump
  }
  __syncthreads();
  if (threadIdx.x == 0) {
    const int prev = atomicAdd((int*)(acc + 2), 1);
    if (prev == (int)gridDim.x - 1) {      // last block finalizes
      const float L = atomicAdd(&acc[0], 0.f);   // coherent reads
      const float C = atomicAdd(&acc[1], 0.f);
      out[0] = L / fmaxf(C, 1.f);
    }
  }
}

// ---------------- Launch ----------------
extern "C" void kernel_launch(void* const* d_in, const int* in_sizes, int n_in,
                              void* d_out, int out_size, void* d_ws, size_t ws_size,
                              hipStream_t stream) {
  const float* emb = (const float*)d_in[0];
  const int* cats = (const int*)d_in[1];
  // d_in[2] (font_labels) is unused by the reference.
  float* out = (float*)d_out;

  char* ws = (char*)d_ws;
  float* accv = (float*)ws;                                  // loss, cnt, block counter
  unsigned short* ebf = (unsigned short*)(ws + 256);         // 4 MB bf16 normalized
  float* posP = (float*)(ws + 256 + NROWS * DDIM * 2);       // 64 slots x 8192
  float* sumP = posP + NSLOT * NROWS;

  hipMemsetAsync(accv, 0, 16, stream);
  knorm<<<NROWS / 4, 256, 0, stream>>>(emb, ebf);
  kmain<<<dim3(NRB, NRB), 256, 0, stream>>>(ebf, cats, posP, sumP);
  kmerge<<<NROWS / 256, 256, 0, stream>>>(posP, sumP, accv, out);
}

// Round 8
// 130.232 us; speedup vs baseline: 1.4618x; 1.0845x over previous
//
#include <hip/hip_runtime.h>
#include <stdint.h>

// Problem constants (fixed by setup_inputs)
#define NROWS 8192
#define DDIM 256
#define BN 32              // cols per LDS tile
#define NTILES 16          // tiles per 512-col strip
#define BM 128             // rows per block (4 waves x 32 rows)
#define NRB (NROWS / BM)   // 64 row panels
#define NJ4 16             // 512-col strips
#define NBLK 544           // sum_{I=0..63} (16 - I/4) live triangular blocks
#define NSLOT 80           // 16 row-path (by J4) + 64 col-path (by I) slots

// Scores are computed directly in log2-units: e is scaled by sqrt(log2(e)/0.7)
// so acc = s*log2(e) and exp(s) == exp2(acc). Since s <= 1/0.7, exp2(acc) <= 4.17
// and per-row sums <= ~34k: no overflow, so NO log-sum-exp shift is needed at all.
#define ESCALE 1.4356159f        // sqrt(log2(e)/0.7)
#define LN2F   0.6931471806f
#define NEGBIG (-1e30f)

// Workspace layout (bytes):
// [0,256) accv; [256, 256+2.5M) pm keys (uint, 80*8192); then sums; then ebf.
#define WS_PMK   256
#define WS_NS    (WS_PMK + NSLOT * NROWS * 4)
#define WS_EBF   (WS_NS + NSLOT * NROWS * 4)
#define WS_ZERO16 ((WS_EBF) / 16)          // uint4 count to zero (accv + partials)

typedef __attribute__((ext_vector_type(8))) short short8;   // 8 bf16 = 4 VGPRs
typedef __attribute__((ext_vector_type(4))) float f32x4;    // MFMA 16x16 accumulator

typedef __attribute__((address_space(3))) void lds_void;          // LDS ptr for DMA builtin
typedef const __attribute__((address_space(1))) void gl_void;     // global ptr for DMA builtin

__device__ __forceinline__ unsigned short f2bf(float x) {   // RNE float->bf16
  unsigned int u = __float_as_uint(x);
  u += 0x7fffu + ((u >> 16) & 1u);
  return (unsigned short)(u >> 16);
}

// Monotone float <-> uint key: a<b (non-NaN) <=> fkey(a)<fkey(b). Zero-init key
// (0x00000000) is below every real key -> "never written" sentinel.
__device__ __forceinline__ unsigned fkey(float f) {
  unsigned b = __float_as_uint(f);
  return (b & 0x80000000u) ? ~b : (b | 0x80000000u);
}
__device__ __forceinline__ float funkey(unsigned k) {
  unsigned b = (k & 0x80000000u) ? (k & 0x7fffffffu) : ~k;
  return __uint_as_float(b);
}

// ---------------- Kernel 1: row L2-normalize -> scaled bf16 (+zero partials) ----------------
// 2048 blocks x 256 threads = 524288 threads >= 327696 uint4 slots: each thread
// zeroes at most one uint4 of the accv+partials region (replaces memset dispatch).
__global__ __launch_bounds__(256) void knorm(const float* __restrict__ emb,
                                             unsigned short* __restrict__ ebf,
                                             uint4* __restrict__ zbase) {
  const int zi = blockIdx.x * 256 + threadIdx.x;
  if (zi < WS_ZERO16) zbase[zi] = (uint4){0u, 0u, 0u, 0u};
  const int wave = threadIdx.x >> 6, lane = threadIdx.x & 63;
  const int row = blockIdx.x * 4 + wave;              // one wave per row
  const float4 v = *(const float4*)(emb + row * DDIM + lane * 4);
  float ss = v.x * v.x + v.y * v.y + v.z * v.z + v.w * v.w;
#pragma unroll
  for (int off = 1; off < 64; off <<= 1) ss += __shfl_xor(ss, off, 64);
  const float sc = rsqrtf(ss) * ESCALE;
  ushort4 o;
  o.x = f2bf(v.x * sc); o.y = f2bf(v.y * sc);
  o.z = f2bf(v.z * sc); o.w = f2bf(v.w * sc);
  *(ushort4*)(ebf + row * DDIM + lane * 4) = o;
}

// ---------------- Kernel 2: strip-triangular symmetric sims ----------------
// 1D grid of 544 live blocks -> (I = 128-row panel, J4 = 512-col strip), J4 >= I/4.
// K-loop = up to 16 tiles (R5 amortization); tiles in sub-blocks J < I skipped via
// t0 (wave-uniform). Sub-block J==I: row path only + per-element self-exclusion.
// J>I: row path + column path (symmetry s_ij == s_ji): per-tile quad-reduce ->
// LDS [2][4][128] double-buffer -> flush per completed 128-col sub-block under the
// existing barriers. Plain stores only (unique (row,slot) writers): no atomics, no
// fences in the hot kernel (R6: per-block device-scope fences cost 2.5x). No
// min-waves launch bound (R4: forcing it spills a[2][8] to scratch).
__global__ __launch_bounds__(256) void kmain(const unsigned short* __restrict__ ebf,
                                             const int* __restrict__ cats,
                                             unsigned* __restrict__ posPk,
                                             float* __restrict__ sumP) {
  // Enumerate (I, J4) from linear bid: per I there are 16 - (I>>2) strips.
  int bid = blockIdx.x, I = 0, base = 0;
  for (;; ++I) { const int c = NJ4 - (I >> 2); if (bid < base + c) break; base += c; }
  const int J4 = (I >> 2) + (bid - base);
  const int d = I - 4 * J4;                           // >0 only on boundary strips
  const int t0 = (d > 0) ? 4 * d : 0;                 // first live tile (multiple of 4)

  __shared__ alignas(16) unsigned short smem[2][BN * DDIM];  // 2 x 16 KB
  __shared__ float cpm[2][4][BM], cns[2][4][BM];             // col partials, 8 KB
  const int tid = threadIdx.x;
  const int lane = tid & 63, wave = tid >> 6;
  const int lane15 = lane & 15, quad = lane >> 4;
  const int rowG = I * BM + wave * 32;                // this wave's 32 rows (m=2)
  const int col0 = J4 * (NTILES * BN);

  // A fragments for the whole block live in registers: a[m][kk] covers
  // rows rowG+m*16+(lane&15), k = kk*32 + quad*8 .. +7   (64 VGPRs)
  short8 a[2][8];
#pragma unroll
  for (int m = 0; m < 2; ++m)
#pragma unroll
    for (int kk = 0; kk < 8; ++kk)
      a[m][kk] = *(const short8*)(ebf + (rowG + m * 16 + lane15) * DDIM + kk * 32 + quad * 8);

  // Per-lane C-layout row categories: row = quad*4 + r (+ m*16)
  int cati[2][4];
#pragma unroll
  for (int m = 0; m < 2; ++m)
#pragma unroll
    for (int r = 0; r < 4; ++r)
      cati[m][r] = cats[rowG + m * 16 + quad * 4 + r];

  // Is this lane the diagonal element (row==col) within a diagonal 16x16 tile?
  bool dlr[4];
#pragma unroll
  for (int r = 0; r < 4; ++r) dlr[r] = (lane15 == quad * 4 + r);

  float pm[2][4], ns[2][4];
#pragma unroll
  for (int m = 0; m < 2; ++m)
#pragma unroll
    for (int r = 0; r < 4; ++r) { pm[m][r] = NEGBIG; ns[m][r] = 0.f; }

  // Async-stage one B tile (1024 16B chunks) into buffer `buf`: 4 DMA per thread.
  // Thread (w,l) takes chunks p = c*256 + w*64 + l; LDS byte = p*16 decomposes as
  // wave-uniform (c*4096 + w*1024) + l*16. Global: kc = c*8 + w*2 + (l>>5), col = l&31.
#define STAGE(t, buf)                                                           \
  {                                                                             \
    const unsigned short* g = ebf +                                             \
        (size_t)(col0 + (t) * BN + (lane & 31)) * DDIM +                        \
        (wave * 2 + (lane >> 5)) * 8;                                           \
    char* lb = (char*)&smem[(buf)][0] + wave * 1024;                            \
    _Pragma("unroll")                                                           \
    for (int c = 0; c < 4; ++c)                                                 \
      __builtin_amdgcn_global_load_lds((gl_void*)(g + c * 64),                  \
                                       (lds_void*)(lb + c * 4096), 16, 0, 0);   \
  }

  STAGE(t0, t0 & 1);

  for (int t = t0; t < NTILES; ++t) {
    __syncthreads();                       // tile t's DMA drained; prev reads done
    // Flush col partials of the just-completed 128-col sub-block (all its tiles
    // done by all waves, per barrier). Reads buf (g-1)&1; current group writes
    // the other buffer -> no race. Waves 2,3 proceed into tile t meanwhile.
    if ((t & 3) == 0 && t > t0) {
      const int jprev = 4 * J4 + (t >> 2) - 1;
      if (jprev > I && tid < BM) {
        const int pb = ((t >> 2) - 1) & 1;
        const float p = fmaxf(fmaxf(cpm[pb][0][tid], cpm[pb][1][tid]),
                              fmaxf(cpm[pb][2][tid], cpm[pb][3][tid]));
        const float n = cns[pb][0][tid] + cns[pb][1][tid] +
                        cns[pb][2][tid] + cns[pb][3][tid];
        posPk[(NJ4 + I) * NROWS + jprev * BM + tid] = fkey(p);
        sumP [(NJ4 + I) * NROWS + jprev * BM + tid] = n;
      }
    }
    if (t + 1 < NTILES) STAGE(t + 1, (t + 1) & 1);   // overlaps this tile's MFMA
    const char* bb = (const char*)&smem[t & 1][0];
    const int colBase = col0 + t * BN;
    const int jt = colBase >> 7;                     // 128-col sub-block index
    const bool colPath = (jt > I);
    const int cjt[2] = {cats[colBase + lane15], cats[colBase + 16 + lane15]};

#pragma unroll
    for (int nt = 0; nt < 2; ++nt) {
      // Batch the 8 B-fragment reads ahead of the MFMA cluster.
      short8 b[8];
#pragma unroll
      for (int kk = 0; kk < 8; ++kk)
        b[kk] = *(const short8*)(bb + kk * 2048 + quad * 512 + nt * 256 + lane15 * 16);
      f32x4 acc0 = {0.f, 0.f, 0.f, 0.f}, acc1 = {0.f, 0.f, 0.f, 0.f};
      __builtin_amdgcn_s_setprio(1);       // T5: favor MFMA-issuing wave
#pragma unroll
      for (int kk = 0; kk < 8; ++kk) {
        acc0 = __builtin_amdgcn_mfma_f32_16x16x32_bf16(a[0][kk], b[kk], acc0, 0, 0, 0);
        acc1 = __builtin_amdgcn_mfma_f32_16x16x32_bf16(a[1][kk], b[kk], acc1, 0, 0, 0);
      }
      __builtin_amdgcn_s_setprio(0);
      const int cj = cjt[nt];
      // Diagonal 16x16 tiles only exist inside the diagonal sub-block (jt==I).
      const bool dg0 = (rowG == colBase + nt * 16);
      const bool dg1 = (rowG + 16 == colBase + nt * 16);
      float cpmv = NEGBIG, cnsv = 0.f;     // lane's column partial (col=colBase+nt*16+lane15)
#pragma unroll
      for (int m = 0; m < 2; ++m) {
        const bool dg = m ? dg1 : dg0;
#pragma unroll
        for (int r = 0; r < 4; ++r) {
          const float s = m ? acc1[r] : acc0[r];      // score in log2-units
          const float e = __builtin_amdgcn_exp2f(s);
          const bool same = (cj == cati[m][r]);
          float psv = same ? s : NEGBIG;              // positive candidate
          if (dg) psv = dlr[r] ? NEGBIG : psv;        // exclude self (diag sub-block)
          pm[m][r] = fmaxf(pm[m][r], psv);
          const float ev = same ? 0.f : e;
          ns[m][r] += ev;                             // row negative sum-of-exp
          cpmv = fmaxf(cpmv, psv);                    // col path (symmetry)
          cnsv += ev;
        }
      }
      if (colPath) {
        // Lanes sharing lane15 across quads hold the same column, different rows.
        cpmv = fmaxf(cpmv, __shfl_xor(cpmv, 16, 64)); cnsv += __shfl_xor(cnsv, 16, 64);
        cpmv = fmaxf(cpmv, __shfl_xor(cpmv, 32, 64)); cnsv += __shfl_xor(cnsv, 32, 64);
        if (quad == 0) {
          const int cc = (colBase & 127) + nt * 16 + lane15;
          const int pb = (t >> 2) & 1;
          cpm[pb][wave][cc] = cpmv; cns[pb][wave][cc] = cnsv;
        }
      }
    }
  }

  __syncthreads();                         // all waves' last-group col writes done
  // Final col flush: last sub-block of the strip (group 3, buffer 1).
  {
    const int jlast = 4 * J4 + 3;
    if (jlast > I && tid < BM) {
      const float p = fmaxf(fmaxf(cpm[1][0][tid], cpm[1][1][tid]),
                            fmaxf(cpm[1][2][tid], cpm[1][3][tid]));
      const float n = cns[1][0][tid] + cns[1][1][tid] +
                      cns[1][2][tid] + cns[1][3][tid];
      posPk[(NJ4 + I) * NROWS + jlast * BM + tid] = fkey(p);
      sumP [(NJ4 + I) * NROWS + jlast * BM + tid] = n;
    }
  }
  // Row path: reduce across the 16 lanes of each quad (they share rows quad*4+r),
  // store into slot J4 (unique writer per (row, slot)).
#pragma unroll
  for (int off = 1; off < 16; off <<= 1) {
#pragma unroll
    for (int m = 0; m < 2; ++m)
#pragma unroll
      for (int r = 0; r < 4; ++r) {
        pm[m][r] = fmaxf(pm[m][r], __shfl_xor(pm[m][r], off, 64));
        ns[m][r] += __shfl_xor(ns[m][r], off, 64);
      }
  }
  if (lane15 == 0) {
#pragma unroll
    for (int m = 0; m < 2; ++m)
#pragma unroll
      for (int r = 0; r < 4; ++r) {
        const int row = rowG + m * 16 + quad * 4 + r;
        posPk[J4 * NROWS + row] = fkey(pm[m][r]);
        sumP [J4 * NROWS + row] = ns[m][r];
      }
  }
}

// ---------------- Kernel 3: merge 80 slots, per-row loss, reduce, finalize ----------------
__global__ __launch_bounds__(256) void kmerge(const unsigned* __restrict__ posPk,
                                              const float* __restrict__ sumP,
                                              float* __restrict__ acc,
                                              float* __restrict__ out) {
  const int row = blockIdx.x * 256 + threadIdx.x;
  unsigned kmax = 0u; float ns = 0.f;
#pragma unroll 8
  for (int s = 0; s < NSLOT; ++s) {
    kmax = max(kmax, posPk[s * NROWS + row]);   // key 0 = never written
    ns += sumP[s * NROWS + row];
  }
  const float pm = funkey(kmax);
  const bool valid = (pm > -1e29f) && (ns > 0.f);
  // pm is pos*log2(e); loss = -pos + ln(exp2(pm) + sum_neg exp(s))   (no shift needed)
  float loss = valid ? (logf(__builtin_amdgcn_exp2f(pm) + ns) - pm * LN2F) : 0.f;
  float cnt = valid ? 1.f : 0.f;
#pragma unroll
  for (int off = 1; off < 64; off <<= 1) {
    loss += __shfl_xor(loss, off, 64);
    cnt += __shfl_xor(cnt, off, 64);
  }
  if ((threadIdx.x & 63) == 0) {
    atomicAdd(&acc[0], loss);
    atomicAdd(&acc[1], cnt);
    __threadfence();                       // my adds visible before the counter bump
  }
  __syncthreads();
  if (threadIdx.x == 0) {
    const int prev = atomicAdd((int*)(acc + 2), 1);
    if (prev == (int)gridDim.x - 1) {      // last block finalizes
      const float L = atomicAdd(&acc[0], 0.f);   // coherent reads
      const float C = atomicAdd(&acc[1], 0.f);
      out[0] = L / fmaxf(C, 1.f);
    }
  }
}

// ---------------- Launch ----------------
extern "C" void kernel_launch(void* const* d_in, const int* in_sizes, int n_in,
                              void* d_out, int out_size, void* d_ws, size_t ws_size,
                              hipStream_t stream) {
  const float* emb = (const float*)d_in[0];
  const int* cats = (const int*)d_in[1];
  // d_in[2] (font_labels) is unused by the reference.
  float* out = (float*)d_out;

  char* ws = (char*)d_ws;
  float* accv = (float*)ws;                                  // loss, cnt, block counter
  unsigned* posPk = (unsigned*)(ws + WS_PMK);                // 80 slots x 8192 keys
  float* sumP = (float*)(ws + WS_NS);                        // 80 slots x 8192 sums
  unsigned short* ebf = (unsigned short*)(ws + WS_EBF);      // 4 MB bf16 normalized

  knorm<<<NROWS / 4, 256, 0, stream>>>(emb, ebf, (uint4*)ws);
  kmain<<<NBLK, 256, 0, stream>>>(ebf, cats, posPk, sumP);
  kmerge<<<NROWS / 256, 256, 0, stream>>>(posPk, sumP, accv, out);
}

// Round 9
// 124.833 us; speedup vs baseline: 1.5250x; 1.0433x over previous
//
#include <hip/hip_runtime.h>
#include <stdint.h>

// Problem constants (fixed by setup_inputs)
#define NROWS 8192
#define DDIM 256
#define BN 32              // cols per LDS tile
#define NTILES 8           // tiles per 256-col strip
#define BM 128             // rows per block (4 waves x 32 rows)
#define NRB (NROWS / BM)   // 64 row panels
#define NJ2 32             // 256-col strips
#define NBLK 1056          // sum_{I=0..63} (32 - I/2) live triangular blocks
#define NSLOT 96           // 32 row-path (by J2) + 64 col-path (by I) slots

// Scores are computed directly in log2-units: e is scaled by sqrt(log2(e)/0.7)
// so acc = s*log2(e) and exp(s) == exp2(acc). Since s <= 1/0.7, exp2(acc) <= 4.17
// and per-row sums <= ~34k: no overflow, so NO log-sum-exp shift is needed at all.
#define ESCALE 1.4356159f        // sqrt(log2(e)/0.7)
#define LN2F   0.6931471806f
#define NEGBIG (-1e30f)

// Workspace layout (bytes):
// [0,256) accv; then pm keys (uint, 96*8192); then sums; then ebf.
#define WS_PMK   256
#define WS_NS    (WS_PMK + NSLOT * NROWS * 4)
#define WS_EBF   (WS_NS + NSLOT * NROWS * 4)
#define WS_ZERO16 ((WS_EBF) / 16)          // uint4 count to zero (accv + partials)

typedef __attribute__((ext_vector_type(8))) short short8;   // 8 bf16 = 4 VGPRs
typedef __attribute__((ext_vector_type(4))) float f32x4;    // MFMA 16x16 accumulator

typedef __attribute__((address_space(3))) void lds_void;          // LDS ptr for DMA builtin
typedef const __attribute__((address_space(1))) void gl_void;     // global ptr for DMA builtin

__device__ __forceinline__ unsigned short f2bf(float x) {   // RNE float->bf16
  unsigned int u = __float_as_uint(x);
  u += 0x7fffu + ((u >> 16) & 1u);
  return (unsigned short)(u >> 16);
}

// Monotone float <-> uint key: a<b (non-NaN) <=> fkey(a)<fkey(b). Zero-init key
// (0x00000000) is below every real key -> "never written" sentinel.
__device__ __forceinline__ unsigned fkey(float f) {
  unsigned b = __float_as_uint(f);
  return (b & 0x80000000u) ? ~b : (b | 0x80000000u);
}
__device__ __forceinline__ float funkey(unsigned k) {
  unsigned b = (k & 0x80000000u) ? (k & 0x7fffffffu) : ~k;
  return __uint_as_float(b);
}

// ---------------- Kernel 1: row L2-normalize -> scaled bf16 (+zero partials) ----------------
// 2048 blocks x 256 threads = 524288 threads >= 393232 uint4 slots: each thread
// zeroes at most one uint4 of the accv+partials region (replaces memset dispatch).
__global__ __launch_bounds__(256) void knorm(const float* __restrict__ emb,
                                             unsigned short* __restrict__ ebf,
                                             uint4* __restrict__ zbase) {
  const int zi = blockIdx.x * 256 + threadIdx.x;
  if (zi < WS_ZERO16) zbase[zi] = (uint4){0u, 0u, 0u, 0u};
  const int wave = threadIdx.x >> 6, lane = threadIdx.x & 63;
  const int row = blockIdx.x * 4 + wave;              // one wave per row
  const float4 v = *(const float4*)(emb + row * DDIM + lane * 4);
  float ss = v.x * v.x + v.y * v.y + v.z * v.z + v.w * v.w;
#pragma unroll
  for (int off = 1; off < 64; off <<= 1) ss += __shfl_xor(ss, off, 64);
  const float sc = rsqrtf(ss) * ESCALE;
  ushort4 o;
  o.x = f2bf(v.x * sc); o.y = f2bf(v.y * sc);
  o.z = f2bf(v.z * sc); o.w = f2bf(v.w * sc);
  *(ushort4*)(ebf + row * DDIM + lane * 4) = o;
}

// ---------------- Kernel 2: strip-triangular symmetric sims ----------------
// 1D grid of 1056 live blocks -> (I = 128-row panel, J2 = 256-col strip), with
// strip end > panel start (upper triangle incl. diagonal). 4.125 blocks/CU at
// 40 KB LDS (R8's 544-block grid left CUs half-empty: occupancy 11.5%).
// Sub-blocks (128 cols) below the diagonal are skipped via t0; diagonal sub-block
// contributes row path only (+ self-exclusion); above-diagonal sub-blocks also
// contribute the column path by symmetry (quad shuffle -> LDS -> per-sub-block
// flush). Plain stores, unique (row,slot) writers: no atomics/fences in the hot
// kernel (R6: per-block device-scope fences cost 2.5x). No min-waves launch bound
// (R4: forcing it spills a[2][8] to scratch).
__global__ __launch_bounds__(256) void kmain(const unsigned short* __restrict__ ebf,
                                             const int* __restrict__ cats,
                                             unsigned* __restrict__ posPk,
                                             float* __restrict__ sumP) {
  // Enumerate (I, J2) from linear bid: per I there are 32 - (I>>1) strips.
  int bid = blockIdx.x, I = 0, base = 0;
  for (;; ++I) { const int c = NJ2 - (I >> 1); if (bid < base + c) break; base += c; }
  const int J2 = (I >> 1) + (bid - base);
  const int col0 = J2 * (NTILES * BN);
  const int t0g = (I * BM - col0) / BN;
  const int t0 = t0g > 0 ? t0g : 0;                   // first live tile (0 or 4)

  __shared__ alignas(16) unsigned short smem[2][BN * DDIM];  // 2 x 16 KB
  __shared__ float cpm[2][4][BM], cns[2][4][BM];             // col partials, 8 KB
  const int tid = threadIdx.x;
  const int lane = tid & 63, wave = tid >> 6;
  const int lane15 = lane & 15, quad = lane >> 4;
  const int rowG = I * BM + wave * 32;                // this wave's 32 rows (m=2)

  // A fragments for the whole block live in registers: a[m][kk] covers
  // rows rowG+m*16+(lane&15), k = kk*32 + quad*8 .. +7   (64 VGPRs)
  short8 a[2][8];
#pragma unroll
  for (int m = 0; m < 2; ++m)
#pragma unroll
    for (int kk = 0; kk < 8; ++kk)
      a[m][kk] = *(const short8*)(ebf + (rowG + m * 16 + lane15) * DDIM + kk * 32 + quad * 8);

  // Per-lane C-layout row categories: row = quad*4 + r (+ m*16)
  int cati[2][4];
#pragma unroll
  for (int m = 0; m < 2; ++m)
#pragma unroll
    for (int r = 0; r < 4; ++r)
      cati[m][r] = cats[rowG + m * 16 + quad * 4 + r];

  // Is this lane the diagonal element (row==col) within a diagonal 16x16 tile?
  bool dlr[4];
#pragma unroll
  for (int r = 0; r < 4; ++r) dlr[r] = (lane15 == quad * 4 + r);

  float pm[2][4], ns[2][4];
#pragma unroll
  for (int m = 0; m < 2; ++m)
#pragma unroll
    for (int r = 0; r < 4; ++r) { pm[m][r] = NEGBIG; ns[m][r] = 0.f; }

  // Async-stage one B tile (1024 16B chunks) into buffer `buf`: 4 DMA per thread.
  // Thread (w,l) takes chunks p = c*256 + w*64 + l; LDS byte = p*16 decomposes as
  // wave-uniform (c*4096 + w*1024) + l*16. Global: kc = c*8 + w*2 + (l>>5), col = l&31.
#define STAGE(t, buf)                                                           \
  {                                                                             \
    const unsigned short* g = ebf +                                             \
        (size_t)(col0 + (t) * BN + (lane & 31)) * DDIM +                        \
        (wave * 2 + (lane >> 5)) * 8;                                           \
    char* lb = (char*)&smem[(buf)][0] + wave * 1024;                            \
    _Pragma("unroll")                                                           \
    for (int c = 0; c < 4; ++c)                                                 \
      __builtin_amdgcn_global_load_lds((gl_void*)(g + c * 64),                  \
                                       (lds_void*)(lb + c * 4096), 16, 0, 0);   \
  }

  STAGE(t0, t0 & 1);

  for (int t = t0; t < NTILES; ++t) {
    __syncthreads();                       // tile t's DMA drained; prev reads done
    // Flush col partials of the just-completed 128-col sub-block (all its tiles
    // done by all waves, per barrier). Reads buffer pb=(g-1)&1; tile t's writers
    // use the other buffer -> no race.
    if ((t & 3) == 0 && t > t0) {
      const int jprev = (col0 >> 7) + (t >> 2) - 1;
      if (jprev > I && tid < BM) {
        const int pb = ((t >> 2) - 1) & 1;
        const float p = fmaxf(fmaxf(cpm[pb][0][tid], cpm[pb][1][tid]),
                              fmaxf(cpm[pb][2][tid], cpm[pb][3][tid]));
        const float n = cns[pb][0][tid] + cns[pb][1][tid] +
                        cns[pb][2][tid] + cns[pb][3][tid];
        posPk[(NJ2 + I) * NROWS + jprev * BM + tid] = fkey(p);
        sumP [(NJ2 + I) * NROWS + jprev * BM + tid] = n;
      }
    }
    if (t + 1 < NTILES) STAGE(t + 1, (t + 1) & 1);   // overlaps this tile's MFMA
    const char* bb = (const char*)&smem[t & 1][0];
    const int colBase = col0 + t * BN;
    const int jt = colBase >> 7;                     // 128-col sub-block index
    const bool colPath = (jt > I);
    const int cjt[2] = {cats[colBase + lane15], cats[colBase + 16 + lane15]};

#pragma unroll
    for (int nt = 0; nt < 2; ++nt) {
      // Batch the 8 B-fragment reads ahead of the MFMA cluster.
      short8 b[8];
#pragma unroll
      for (int kk = 0; kk < 8; ++kk)
        b[kk] = *(const short8*)(bb + kk * 2048 + quad * 512 + nt * 256 + lane15 * 16);
      f32x4 acc0 = {0.f, 0.f, 0.f, 0.f}, acc1 = {0.f, 0.f, 0.f, 0.f};
      __builtin_amdgcn_s_setprio(1);       // T5: favor MFMA-issuing wave
#pragma unroll
      for (int kk = 0; kk < 8; ++kk) {
        acc0 = __builtin_amdgcn_mfma_f32_16x16x32_bf16(a[0][kk], b[kk], acc0, 0, 0, 0);
        acc1 = __builtin_amdgcn_mfma_f32_16x16x32_bf16(a[1][kk], b[kk], acc1, 0, 0, 0);
      }
      __builtin_amdgcn_s_setprio(0);
      const int cj = cjt[nt];
      // Diagonal 16x16 tiles only exist inside the diagonal sub-block (jt==I).
      const bool dg0 = (rowG == colBase + nt * 16);
      const bool dg1 = (rowG + 16 == colBase + nt * 16);
      float cpmv = NEGBIG, cnsv = 0.f;     // lane's column partial (col=colBase+nt*16+lane15)
#pragma unroll
      for (int m = 0; m < 2; ++m) {
        const bool dg = m ? dg1 : dg0;
#pragma unroll
        for (int r = 0; r < 4; ++r) {
          const float s = m ? acc1[r] : acc0[r];      // score in log2-units
          const float e = __builtin_amdgcn_exp2f(s);
          const bool same = (cj == cati[m][r]);
          float psv = same ? s : NEGBIG;              // positive candidate
          if (dg) psv = dlr[r] ? NEGBIG : psv;        // exclude self (diag sub-block)
          pm[m][r] = fmaxf(pm[m][r], psv);
          const float ev = same ? 0.f : e;
          ns[m][r] += ev;                             // row negative sum-of-exp
          cpmv = fmaxf(cpmv, psv);                    // col path (symmetry)
          cnsv += ev;
        }
      }
      if (colPath) {
        // Lanes sharing lane15 across quads hold the same column, different rows.
        cpmv = fmaxf(cpmv, __shfl_xor(cpmv, 16, 64)); cnsv += __shfl_xor(cnsv, 16, 64);
        cpmv = fmaxf(cpmv, __shfl_xor(cpmv, 32, 64)); cnsv += __shfl_xor(cnsv, 32, 64);
        if (quad == 0) {
          const int cc = (colBase & 127) + nt * 16 + lane15;
          const int pb = (t >> 2) & 1;
          cpm[pb][wave][cc] = cpmv; cns[pb][wave][cc] = cnsv;
        }
      }
    }
  }

  __syncthreads();                         // all waves' last-sub-block col writes done
  // Final col flush: last 128-col sub-block of the strip (group 1, buffer 1).
  {
    const int jlast = (col0 >> 7) + 1;
    if (jlast > I && tid < BM) {
      const float p = fmaxf(fmaxf(cpm[1][0][tid], cpm[1][1][tid]),
                            fmaxf(cpm[1][2][tid], cpm[1][3][tid]));
      const float n = cns[1][0][tid] + cns[1][1][tid] +
                      cns[1][2][tid] + cns[1][3][tid];
      posPk[(NJ2 + I) * NROWS + jlast * BM + tid] = fkey(p);
      sumP [(NJ2 + I) * NROWS + jlast * BM + tid] = n;
    }
  }
  // Row path: reduce across the 16 lanes of each quad (they share rows quad*4+r),
  // store into slot J2 (unique writer per (row, slot)).
#pragma unroll
  for (int off = 1; off < 16; off <<= 1) {
#pragma unroll
    for (int m = 0; m < 2; ++m)
#pragma unroll
      for (int r = 0; r < 4; ++r) {
        pm[m][r] = fmaxf(pm[m][r], __shfl_xor(pm[m][r], off, 64));
        ns[m][r] += __shfl_xor(ns[m][r], off, 64);
      }
  }
  if (lane15 == 0) {
#pragma unroll
    for (int m = 0; m < 2; ++m)
#pragma unroll
      for (int r = 0; r < 4; ++r) {
        const int row = rowG + m * 16 + quad * 4 + r;
        posPk[J2 * NROWS + row] = fkey(pm[m][r]);
        sumP [J2 * NROWS + row] = ns[m][r];
      }
  }
}

// ---------------- Kernel 3: merge 96 slots, per-row loss, reduce, finalize ----------------
__global__ __launch_bounds__(256) void kmerge(const unsigned* __restrict__ posPk,
                                              const float* __restrict__ sumP,
                                              float* __restrict__ acc,
                                              float* __restrict__ out) {
  const int row = blockIdx.x * 256 + threadIdx.x;
  unsigned kmax = 0u; float ns = 0.f;
#pragma unroll 8
  for (int s = 0; s < NSLOT; ++s) {
    kmax = max(kmax, posPk[s * NROWS + row]);   // key 0 = never written
    ns += sumP[s * NROWS + row];
  }
  const float pm = funkey(kmax);
  const bool valid = (pm > -1e29f) && (ns > 0.f);
  // pm is pos*log2(e); loss = -pos + ln(exp2(pm) + sum_neg exp(s))   (no shift needed)
  float loss = valid ? (logf(__builtin_amdgcn_exp2f(pm) + ns) - pm * LN2F) : 0.f;
  float cnt = valid ? 1.f : 0.f;
#pragma unroll
  for (int off = 1; off < 64; off <<= 1) {
    loss += __shfl_xor(loss, off, 64);
    cnt += __shfl_xor(cnt, off, 64);
  }
  if ((threadIdx.x & 63) == 0) {
    atomicAdd(&acc[0], loss);
    atomicAdd(&acc[1], cnt);
    __threadfence();                       // my adds visible before the counter bump
  }
  __syncthreads();
  if (threadIdx.x == 0) {
    const int prev = atomicAdd((int*)(acc + 2), 1);
    if (prev == (int)gridDim.x - 1) {      // last block finalizes
      const float L = atomicAdd(&acc[0], 0.f);   // coherent reads
      const float C = atomicAdd(&acc[1], 0.f);
      out[0] = L / fmaxf(C, 1.f);
    }
  }
}

// ---------------- Launch ----------------
extern "C" void kernel_launch(void* const* d_in, const int* in_sizes, int n_in,
                              void* d_out, int out_size, void* d_ws, size_t ws_size,
                              hipStream_t stream) {
  const float* emb = (const float*)d_in[0];
  const int* cats = (const int*)d_in[1];
  // d_in[2] (font_labels) is unused by the reference.
  float* out = (float*)d_out;

  char* ws = (char*)d_ws;
  float* accv = (float*)ws;                                  // loss, cnt, block counter
  unsigned* posPk = (unsigned*)(ws + WS_PMK);                // 96 slots x 8192 keys
  float* sumP = (float*)(ws + WS_NS);                        // 96 slots x 8192 sums
  unsigned short* ebf = (unsigned short*)(ws + WS_EBF);      // 4 MB bf16 normalized

  knorm<<<NROWS / 4, 256, 0, stream>>>(emb, ebf, (uint4*)ws);
  kmain<<<NBLK, 256, 0, stream>>>(ebf, cats, posPk, sumP);
  kmerge<<<NROWS / 256, 256, 0, stream>>>(posPk, sumP, accv, out);
}